// Round 11
// baseline (363.680 us; speedup 1.0000x reference)
//
#include <hip/hip_runtime.h>
#include <math.h>

// Problem constants: B=8, spatial 64x64 (HW=4096), C_mid=256, C=128, N=9 taps.
// All inputs/outputs are float32.
typedef const float* fp;
typedef __attribute__((ext_vector_type(8))) short short8;   // 8 bf16 = 4 VGPRs (MFMA A/B frag)
typedef __attribute__((ext_vector_type(4))) float f32x4;    // MFMA C/D frag

__device__ __forceinline__ unsigned short f2bf(float f){    // RTNE float->bf16
    unsigned u = __float_as_uint(f);
    u += 0x7fff + ((u >> 16) & 1);
    return (unsigned short)(u >> 16);
}

// ---------------- K0a: dcn_w (o,c,9) -> Wbf[n][o][c] bf16
__global__ __launch_bounds__(256) void k_wbf(fp dcn_w, unsigned short* Wbf){
    int i = blockIdx.x*256 + threadIdx.x;       // 147456
    int c = i & 127, o = (i >> 7) & 127, n = i >> 14;
    Wbf[i] = f2bf(dcn_w[o*1152 + c*9 + n]);
}

// ---------------- K0b: p_w/m_w -> Wpm[n][32q][128c] bf16 (q>=27 zero)
__global__ __launch_bounds__(256) void k_wpm(fp pw, fp mw, unsigned short* Wpm){
    int i = blockIdx.x*256 + threadIdx.x;       // 36864 = 9*32*128
    int c = i & 127, q = (i >> 7) & 31, n = i >> 12;
    float v = 0.f;
    if(q < 18)      v = pw[q*1152 + c*9 + n];
    else if(q < 27) v = mw[(q-18)*1152 + c*9 + n];
    Wpm[i] = f2bf(v);
}

// ---------------- K1: fused upsample+concat+depthwise256 -> Bo (8,256,64,64)
__global__ __launch_bounds__(256) void k_updw256(fp x1, fp x2, fp w, fp bias, float* Bo){
    __shared__ float sA[66*68];
    int bid = blockIdx.x;
    int c = bid & 255, b = bid >> 8;
    int tid = threadIdx.x;
    for(int j = tid; j < 4356; j += 256){
        int r = j / 66, cpos = j - r*66;
        int yy = r - 1, xx = cpos - 1;
        float val = 0.f;
        if(yy >= 0 && yy < 64 && xx >= 0 && xx < 64){
            if(c < 128){
                val = x2[((b*128+c)<<12) + (yy<<6) + xx];
            } else {
                int cc = c - 128;
                const float s = 31.0f/63.0f;
                float fy = yy*s, fx = xx*s;
                int iy = (int)fy; if (iy > 30) iy = 30;
                int ix = (int)fx; if (ix > 30) ix = 30;
                float ty = fy - (float)iy, tx = fx - (float)ix;
                fp src = x1 + ((b*128+cc)<<10);
                float v00 = src[iy*32+ix],     v01 = src[iy*32+ix+1];
                float v10 = src[(iy+1)*32+ix], v11 = src[(iy+1)*32+ix+1];
                val = (v00*(1.f-ty)+v10*ty)*(1.f-tx) + (v01*(1.f-ty)+v11*ty)*tx;
            }
        }
        sA[r*68 + cpos] = val;
    }
    __syncthreads();
    float w0=w[c*9+0], w1=w[c*9+1], w2=w[c*9+2];
    float w3=w[c*9+3], w4=w[c*9+4], w5=w[c*9+5];
    float w6=w[c*9+6], w7=w[c*9+7], w8=w[c*9+8];
    float bv = bias[c];
    float* dst = Bo + ((size_t)(b*256+c)<<12);
    for(int j = tid; j < 4096; j += 256){
        int y = j >> 6, x = j & 63;
        const float* r0 = &sA[y*68 + x];
        float acc = bv
            + w0*r0[0]   + w1*r0[1]   + w2*r0[2]
            + w3*r0[68]  + w4*r0[69]  + w5*r0[70]
            + w6*r0[136] + w7*r0[137] + w8*r0[138];
        dst[j] = acc;
    }
}

// ---------------- K3: pointwise 256->128 + bias -> Ccl (channel-last only)
__global__ __launch_bounds__(256) void k_pw(const float* Bi, fp w, fp bias, float* Ccl){
    __shared__ float sIn[256*32];
    int bid = blockIdx.x;                       // 1024
    int b = bid >> 7;
    int pix0 = (bid & 127) << 5;
    int tid = threadIdx.x;
    for(int j = tid; j < 256*32; j += 256){
        int c = j >> 5, p = j & 31;
        sIn[j] = Bi[((b*256 + c)<<12) + pix0 + p];
    }
    __syncthreads();
    int og = tid >> 3, pg = tid & 7;
    int o0 = og*4, p0 = pg*4;
    float acc[4][4];
    #pragma unroll
    for(int i=0;i<4;i++){ float bv=bias[o0+i];
        #pragma unroll
        for(int j=0;j<4;j++) acc[i][j]=bv; }
    for(int c=0;c<256;c++){
        float4 xv = *(const float4*)&sIn[(c<<5)+p0];
        float w0=w[(o0+0)*256+c], w1=w[(o0+1)*256+c];
        float w2=w[(o0+2)*256+c], w3=w[(o0+3)*256+c];
        acc[0][0]+=w0*xv.x; acc[0][1]+=w0*xv.y; acc[0][2]+=w0*xv.z; acc[0][3]+=w0*xv.w;
        acc[1][0]+=w1*xv.x; acc[1][1]+=w1*xv.y; acc[1][2]+=w1*xv.z; acc[1][3]+=w1*xv.w;
        acc[2][0]+=w2*xv.x; acc[2][1]+=w2*xv.y; acc[2][2]+=w2*xv.z; acc[2][3]+=w2*xv.w;
        acc[3][0]+=w3*xv.x; acc[3][1]+=w3*xv.y; acc[3][2]+=w3*xv.z; acc[3][3]+=w3*xv.w;
    }
    #pragma unroll
    for(int j=0;j<4;j++){
        int px = pix0 + p0 + j;
        *(float4*)&Ccl[((size_t)(b<<12) + px)*128 + o0] =
            make_float4(acc[0][j],acc[1][j],acc[2][j],acc[3][j]);
    }
}

// ---------------- K4: offset(18)+mask(9, sigmoid) 3x3 conv via bf16 MFMA -> OM (8,27,4096)
__global__ __launch_bounds__(256) void k_offmask(fp Ccl, const unsigned short* Wpm,
                                                 fp pb, fp mb, float* OM){
    __shared__ __align__(16) unsigned short sW[32*136];   // [q][c] bf16
    __shared__ __align__(16) unsigned short sX[64*136];   // [px][c] bf16
    int b = blockIdx.x & 7;
    int y = blockIdx.x >> 3;          // output row
    int pix0 = y << 6;
    int tid = threadIdx.x;
    int lane = tid & 63, wave = tid >> 6;
    int m16 = lane & 15, quad = lane >> 4;
    int wp = wave << 4;               // px-subtile
    const float* cb = Ccl + (size_t)(b<<12)*128;

    // ---- probe: D[m][n]=m*(n+100)
    short8 ap = {0,0,0,0,0,0,0,0}, bpr = {0,0,0,0,0,0,0,0};
    if(quad == 0){
        ap[0]  = (short)f2bf((float)m16);
        bpr[0] = (short)f2bf((float)(m16+100));
    }
    f32x4 dp = {0.f,0.f,0.f,0.f};
    dp = __builtin_amdgcn_mfma_f32_16x16x32_bf16(ap, bpr, dp, 0,0,0);
    bool p1 = true;
    #pragma unroll
    for(int r=0;r<4;r++){
        float expP1 = (float)(quad*4+r) * (float)(m16+100);
        p1 = p1 && (fabsf(dp[r]-expP1) < 0.5f);
    }
    bool swapD = (__ballot(p1) != 0xFFFFFFFFFFFFFFFFull);

    f32x4 acc[2];
    acc[0] = (f32x4){0.f,0.f,0.f,0.f};
    acc[1] = (f32x4){0.f,0.f,0.f,0.f};

    for(int n=0;n<9;n++){
        int ky = n/3, kx = n - ky*3;
        int yy = y + ky - 1;
        bool rowok = (yy>=0 && yy<64);
        const int4* wsrc = (const int4*)(Wpm + (n<<12));
        for(int j=tid; j<512; j+=256){
            int q = j >> 4, cg = j & 15;
            *(int4*)&sW[q*136 + (cg<<3)] = wsrc[j];
        }
        #pragma unroll
        for(int it=0; it<8; it++){
            int e = tid + (it<<8);
            int cg = (e & 31) << 2, px = e >> 5;
            int xx = px + kx - 1;
            float4 v = make_float4(0.f,0.f,0.f,0.f);
            if(rowok && xx>=0 && xx<64)
                v = *(const float4*)&cb[(size_t)((yy<<6)+xx)*128 + cg];
            unsigned long long pk = (unsigned long long)f2bf(v.x)
                | ((unsigned long long)f2bf(v.y)<<16)
                | ((unsigned long long)f2bf(v.z)<<32)
                | ((unsigned long long)f2bf(v.w)<<48);
            *(unsigned long long*)&sX[px*136 + cg] = pk;
        }
        __syncthreads();
        #pragma unroll
        for(int ks=0; ks<4; ks++){
            int k0 = ks << 5;
            short8 bfr = *(const short8*)&sX[(wp + m16)*136 + k0 + (quad<<3)];
            #pragma unroll
            for(int qt=0;qt<2;qt++){
                short8 afr = *(const short8*)&sW[((qt<<4) + m16)*136 + k0 + (quad<<3)];
                acc[qt] = __builtin_amdgcn_mfma_f32_16x16x32_bf16(afr, bfr, acc[qt], 0,0,0);
            }
        }
        __syncthreads();
    }
    if(!swapD){
        #pragma unroll
        for(int qt=0;qt<2;qt++){
            int px = pix0 + wp + m16;
            #pragma unroll
            for(int r=0;r<4;r++){
                int q = (qt<<4) + (quad<<2) + r;
                if(q < 27){
                    float v = acc[qt][r] + ((q<18) ? pb[q] : mb[q-18]);
                    if(q>=18) v = 1.f/(1.f+expf(-v));
                    OM[((b*27+q)<<12) + px] = v;
                }
            }
        }
    } else {
        #pragma unroll
        for(int qt=0;qt<2;qt++){
            int q = (qt<<4) + m16;
            if(q < 27){
                float bias = (q<18) ? pb[q] : mb[q-18];
                #pragma unroll
                for(int r=0;r<4;r++){
                    int px = pix0 + wp + (quad<<2) + r;
                    float v = acc[qt][r] + bias;
                    if(q>=18) v = 1.f/(1.f+expf(-v));
                    OM[((b*27+q)<<12) + px] = v;
                }
            }
        }
    }
}

// ---------------- K5: deformable sampling + bf16 MFMA combine + fused BN1-stats.
// Grid 512 = 64 tiles x 8 b (b = blockIdx&7). LDS 53.2 KB -> 3 blocks/CU.
// Gather: one px per 4 threads (gpx=tid>>2, 32ch each); tap meta recomputed per-thread
// in registers (4x redundant, OM loads broadcast). Stats1 (sum/sumsq per channel)
// reduced from acc frags via shfl + LDS + global atomics (replaces k_stats_par).
__global__ __launch_bounds__(256) void k_deform(fp Ccl, fp OM, const unsigned short* Wbf,
                                                float* D, float* stats){
    __shared__ __align__(16) unsigned short sW[128*136];  // [o][c] bf16, 272B rows
    __shared__ __align__(16) unsigned short sX[64*136];   // [px][c] bf16
    __shared__ float sd[128], sq[128];
    int b = blockIdx.x & 7;
    int pix0 = (blockIdx.x >> 3) << 6;
    int tid = threadIdx.x;
    int lane = tid & 63, wave = tid >> 6;
    int m16 = lane & 15, quad = lane >> 4;
    int wo = (wave & 1) << 6;       // o-half: 0/64
    int wp = (wave >> 1) << 5;      // px-half: 0/32
    int gpx = tid >> 2;             // gather px (0..63)
    int cgB = (tid & 3) << 5;       // gather channel base (0/32/64/96)
    const float* omb = OM + b*27*4096;
    const float* cb  = Ccl + (size_t)(b<<12)*128;
    if(tid < 128){ sd[tid] = 0.f; sq[tid] = 0.f; }

    // ---- probe
    short8 ap = {0,0,0,0,0,0,0,0}, bpr = {0,0,0,0,0,0,0,0};
    if(quad == 0){
        ap[0]  = (short)f2bf((float)m16);
        bpr[0] = (short)f2bf((float)(m16+100));
    }
    f32x4 dp = {0.f,0.f,0.f,0.f};
    dp = __builtin_amdgcn_mfma_f32_16x16x32_bf16(ap, bpr, dp, 0,0,0);
    bool p1 = true;
    #pragma unroll
    for(int r=0;r<4;r++){
        float expP1 = (float)(quad*4+r) * (float)(m16+100);
        p1 = p1 && (fabsf(dp[r]-expP1) < 0.5f);
    }
    bool swapD = (__ballot(p1) != 0xFFFFFFFFFFFFFFFFull);

    f32x4 acc[4][2];
    #pragma unroll
    for(int i=0;i<4;i++){
        #pragma unroll
        for(int j=0;j<2;j++) acc[i][j] = (f32x4){0.f,0.f,0.f,0.f};
    }

    for(int n=0;n<9;n++){
        // stage weight tile sW[o][c] = Wbf[n][o][c]
        {
            const int4* src = (const int4*)(Wbf + (n<<14));
            for(int j = tid; j < 2048; j += 256){
                int o = j >> 4, cg = j & 15;
                *(int4*)&sW[o*136 + (cg<<3)] = src[(o<<4) + cg];
            }
        }
        // per-thread tap meta for my px (4x redundant; OM loads broadcast)
        int pix = pix0 + gpx; int y = pix>>6, x = pix&63;
        float offx = omb[(n<<12)+pix];
        float offy = omb[((n+9)<<12)+pix];
        float m    = omb[((n+18)<<12)+pix];
        float pxf = (float)(y + n/3) + offx;
        float pyf = (float)(x + n%3) + offy;
        float fx = floorf(pxf), fy = floorf(pyf);
        float qx0 = fminf(fmaxf(fx,0.f),65.f), qx1 = fminf(fmaxf(fx+1.f,0.f),65.f);
        float qy0 = fminf(fmaxf(fy,0.f),65.f), qy1 = fminf(fmaxf(fy+1.f,0.f),65.f);
        float pxc = fminf(fmaxf(pxf,0.f),65.f), pyc = fminf(fmaxf(pyf,0.f),65.f);
        float g0 = (1.f+(qx0-pxc))*(1.f+(qy0-pyc))*m;
        float g1 = (1.f-(qx1-pxc))*(1.f-(qy1-pyc))*m;
        float g2 = (1.f+(qx0-pxc))*(1.f-(qy1-pyc))*m;
        float g3 = (1.f-(qx1-pxc))*(1.f+(qy0-pyc))*m;
        int ax0=(int)qx0, ax1=(int)qx1, ay0=(int)qy0, ay1=(int)qy1;
        int bs0 = (ax0>=1&&ax0<=64&&ay0>=1&&ay0<=64) ? (((ax0-1)<<6)+(ay0-1)) : -1;
        int bs1 = (ax1>=1&&ax1<=64&&ay1>=1&&ay1<=64) ? (((ax1-1)<<6)+(ay1-1)) : -1;
        int bs2 = (ax0>=1&&ax0<=64&&ay1>=1&&ay1<=64) ? (((ax0-1)<<6)+(ay1-1)) : -1;
        int bs3 = (ax1>=1&&ax1<=64&&ay0>=1&&ay0<=64) ? (((ax1-1)<<6)+(ay0-1)) : -1;
        // gather my px's 32 channels (8 cgroups of 4)
        #pragma unroll
        for(int it=0; it<8; it++){
            int cg = cgB + (it<<2);
            float4 v = make_float4(0.f,0.f,0.f,0.f);
            if(bs0>=0){ float4 r = *(const float4*)&cb[(bs0<<7)+cg];
                v.x+=g0*r.x; v.y+=g0*r.y; v.z+=g0*r.z; v.w+=g0*r.w; }
            if(bs1>=0){ float4 r = *(const float4*)&cb[(bs1<<7)+cg];
                v.x+=g1*r.x; v.y+=g1*r.y; v.z+=g1*r.z; v.w+=g1*r.w; }
            if(bs2>=0){ float4 r = *(const float4*)&cb[(bs2<<7)+cg];
                v.x+=g2*r.x; v.y+=g2*r.y; v.z+=g2*r.z; v.w+=g2*r.w; }
            if(bs3>=0){ float4 r = *(const float4*)&cb[(bs3<<7)+cg];
                v.x+=g3*r.x; v.y+=g3*r.y; v.z+=g3*r.z; v.w+=g3*r.w; }
            unsigned long long pk = (unsigned long long)f2bf(v.x)
                | ((unsigned long long)f2bf(v.y)<<16)
                | ((unsigned long long)f2bf(v.z)<<32)
                | ((unsigned long long)f2bf(v.w)<<48);
            *(unsigned long long*)&sX[gpx*136 + cg] = pk;
        }
        __syncthreads();
        #pragma unroll
        for(int ks=0; ks<4; ks++){
            int k0 = ks << 5;
            short8 bfr[2];
            #pragma unroll
            for(int pt=0;pt<2;pt++)
                bfr[pt] = *(const short8*)&sX[(wp + (pt<<4) + m16)*136 + k0 + (quad<<3)];
            #pragma unroll
            for(int ot=0;ot<4;ot++){
                short8 afr = *(const short8*)&sW[(wo + (ot<<4) + m16)*136 + k0 + (quad<<3)];
                #pragma unroll
                for(int pt=0;pt<2;pt++)
                    acc[ot][pt] = __builtin_amdgcn_mfma_f32_16x16x32_bf16(afr, bfr[pt], acc[ot][pt], 0,0,0);
            }
        }
        __syncthreads();                 // MFMA reads done before next tap's overwrite
    }
    // epilogue: D writes + per-channel sum/sumsq reduction
    if(!swapD){
        #pragma unroll
        for(int ot=0;ot<4;ot++){
            #pragma unroll
            for(int pt=0;pt<2;pt++){
                int px = pix0 + wp + (pt<<4) + m16;
                #pragma unroll
                for(int r=0;r<4;r++){
                    int o = wo + (ot<<4) + (quad<<2) + r;
                    D[((b*128+o)<<12) + px] = acc[ot][pt][r];
                }
            }
        }
        #pragma unroll
        for(int ot=0;ot<4;ot++){
            #pragma unroll
            for(int r=0;r<4;r++){
                float s = acc[ot][0][r] + acc[ot][1][r];
                float s2 = acc[ot][0][r]*acc[ot][0][r] + acc[ot][1][r]*acc[ot][1][r];
                #pragma unroll
                for(int msk=1; msk<16; msk<<=1){
                    s  += __shfl_xor(s, msk, 64);
                    s2 += __shfl_xor(s2, msk, 64);
                }
                if(m16 == 0){
                    int o = wo + (ot<<4) + (quad<<2) + r;
                    atomicAdd(&sd[o], s);
                    atomicAdd(&sq[o], s2);
                }
            }
        }
    } else {
        #pragma unroll
        for(int ot=0;ot<4;ot++){
            #pragma unroll
            for(int pt=0;pt<2;pt++){
                int o = wo + (ot<<4) + m16;
                #pragma unroll
                for(int r=0;r<4;r++){
                    int px = pix0 + wp + (pt<<4) + (quad<<2) + r;
                    D[((b*128+o)<<12) + px] = acc[ot][pt][r];
                }
            }
        }
        #pragma unroll
        for(int ot=0;ot<4;ot++){
            float s = 0.f, s2 = 0.f;
            #pragma unroll
            for(int pt=0;pt<2;pt++){
                #pragma unroll
                for(int r=0;r<4;r++){
                    float v = acc[ot][pt][r];
                    s += v; s2 += v*v;
                }
            }
            #pragma unroll
            for(int msk=16; msk<64; msk<<=1){
                s  += __shfl_xor(s, msk, 64);
                s2 += __shfl_xor(s2, msk, 64);
            }
            if(quad == 0){
                int o = wo + (ot<<4) + m16;
                atomicAdd(&sd[o], s);
                atomicAdd(&sq[o], s2);
            }
        }
    }
    __syncthreads();
    if(tid < 128){
        atomicAdd(&stats[tid],     sd[tid]);
        atomicAdd(&stats[128+tid], sq[tid]);
    }
}

// ---------------- K7: fused BN1+GELU + depthwise128 -> Hs, + atomic stats2 partials
__global__ __launch_bounds__(256) void k_bngelu_dw128(const float* Dsrc, float* stats,
                                                      fp g1, fp b1, fp w, fp bias, float* Hs){
    __shared__ float sG[66*68];
    __shared__ float sd[256], sq[256];
    int bid = blockIdx.x;
    int c = bid & 127, b = bid >> 7;
    int tid = threadIdx.x;
    float mean1 = stats[c] * (1.f/32768.f);
    float var1  = stats[128+c] * (1.f/32768.f) - mean1*mean1;
    float rstd1 = rsqrtf(var1 + 1e-5f);
    float sc = rstd1 * g1[c];
    float sb = b1[c] - mean1*sc;
    const float* dplane = Dsrc + ((size_t)(b*128+c)<<12);
    for(int j = tid; j < 4356; j += 256){
        int r = j / 66, cpos = j - r*66;
        int yy = r - 1, xx = cpos - 1;
        float val = 0.f;
        if(yy >= 0 && yy < 64 && xx >= 0 && xx < 64){
            float v = dplane[(yy<<6)+xx]*sc + sb;
            val = 0.5f*v*(1.0f + erff(v*0.70710678118654752f));
        }
        sG[r*68 + cpos] = val;
    }
    __syncthreads();
    float w0=w[c*9+0], w1=w[c*9+1], w2=w[c*9+2];
    float w3=w[c*9+3], w4=w[c*9+4], w5=w[c*9+5];
    float w6=w[c*9+6], w7=w[c*9+7], w8=w[c*9+8];
    float bv = bias[c];
    float* dst = Hs + ((size_t)(b*128+c)<<12);
    float s = 0.f, s2 = 0.f;
    for(int j = tid; j < 4096; j += 256){
        int y = j >> 6, x = j & 63;
        const float* r0 = &sG[y*68 + x];
        float acc = bv
            + w0*r0[0]   + w1*r0[1]   + w2*r0[2]
            + w3*r0[68]  + w4*r0[69]  + w5*r0[70]
            + w6*r0[136] + w7*r0[137] + w8*r0[138];
        dst[j] = acc;
        s += acc; s2 += acc*acc;
    }
    sd[tid]=s; sq[tid]=s2; __syncthreads();
    for(int off=128; off>0; off>>=1){
        if(tid<off){ sd[tid]+=sd[tid+off]; sq[tid]+=sq[tid+off]; }
        __syncthreads();
    }
    if(tid==0){
        atomicAdd(&stats[256+c], sd[0]);
        atomicAdd(&stats[384+c], sq[0]);
    }
}

// ---------------- BN2 + ReLU -> f32 out (float4; finalizes stats2 sums inline)
__global__ __launch_bounds__(256) void k_bn_relu_out(const float* Hs, const float* stats, fp g, fp bb, float* out){
    int idx = blockIdx.x*256+threadIdx.x;       // 1,048,576 float4
    int c = (idx>>10)&127;
    float mean2 = stats[256+c] * (1.f/32768.f);
    float var2  = stats[384+c] * (1.f/32768.f) - mean2*mean2;
    float rs = rsqrtf(var2 + 1e-5f) * g[c];
    float sb = bb[c] - mean2*rs;
    float4 v = ((const float4*)Hs)[idx];
    float4 o;
    o.x = fmaxf(v.x*rs+sb, 0.f);
    o.y = fmaxf(v.y*rs+sb, 0.f);
    o.z = fmaxf(v.z*rs+sb, 0.f);
    o.w = fmaxf(v.w*rs+sb, 0.f);
    ((float4*)out)[idx] = o;
}

extern "C" void kernel_launch(void* const* d_in, const int* in_sizes, int n_in,
                              void* d_out, int out_size, void* d_ws, size_t ws_size,
                              hipStream_t stream){
    fp x1   = (fp)d_in[0];
    fp x2   = (fp)d_in[1];
    fp dw_w = (fp)d_in[2];  fp dw_b = (fp)d_in[3];
    fp pw_w = (fp)d_in[4];  fp pw_b = (fp)d_in[5];
    fp p_w  = (fp)d_in[6];  fp p_b  = (fp)d_in[7];
    fp m_w  = (fp)d_in[8];  fp m_b  = (fp)d_in[9];
    fp dcn_w= (fp)d_in[10];
    fp bn1g = (fp)d_in[11]; fp bn1b = (fp)d_in[12];
    fp dw2w = (fp)d_in[13]; fp dw2b = (fp)d_in[14];
    fp bn2g = (fp)d_in[15]; fp bn2b = (fp)d_in[16];

    float* ws  = (float*)d_ws;
    float* Bo  = ws;                    // (8,256,4096) = 8,388,608 f ; D reuses after k_pw
    float* Ccl = ws + 8388608;          // (8,4096,128) = 4,194,304 f ; Hs reuses after k_deform
    float* OM  = ws + 12582912;         // (8,27,4096)  =   884,736 f
    unsigned short* Wbf = (unsigned short*)(ws + 13467648);  // 147,456 bf16 (73,728 f)
    unsigned short* Wpm = (unsigned short*)(ws + 13541376);  //  36,864 bf16 (18,432 f)
    float* stats = ws + 13559808;       // 512 f (sum1, sq1, sum2, sq2)
    float* D   = Bo;                    // Bo dead after k_pw
    float* Hs  = Ccl;                   // Ccl dead after k_deform
    float* out = (float*)d_out;

    hipMemsetAsync(stats, 0, 512*sizeof(float), stream);
    k_wbf          <<<576,   256, 0, stream>>>(dcn_w, Wbf);
    k_wpm          <<<144,   256, 0, stream>>>(p_w, m_w, Wpm);
    k_updw256      <<<2048,  256, 0, stream>>>(x1, x2, dw_w, dw_b, Bo);
    k_pw           <<<1024,  256, 0, stream>>>(Bo, pw_w, pw_b, Ccl);
    k_offmask      <<<512,   256, 0, stream>>>(Ccl, Wpm, p_b, m_b, OM);
    k_deform       <<<512,   256, 0, stream>>>(Ccl, OM, Wbf, D, stats);
    k_bngelu_dw128 <<<1024,  256, 0, stream>>>(D, stats, bn1g, bn1b, dw2w, dw2b, Hs);
    k_bn_relu_out  <<<4096,  256, 0, stream>>>(Hs, stats, bn2g, bn2b, out);
}

// Round 12
// 292.356 us; speedup vs baseline: 1.2440x; 1.2440x over previous
//
#include <hip/hip_runtime.h>
#include <math.h>

// Problem constants: B=8, spatial 64x64 (HW=4096), C_mid=256, C=128, N=9 taps.
// All inputs/outputs are float32.
typedef const float* fp;
typedef __attribute__((ext_vector_type(8))) short short8;   // 8 bf16 = 4 VGPRs (MFMA A/B frag)
typedef __attribute__((ext_vector_type(4))) float f32x4;    // MFMA C/D frag

__device__ __forceinline__ unsigned short f2bf(float f){    // RTNE float->bf16
    unsigned u = __float_as_uint(f);
    u += 0x7fff + ((u >> 16) & 1);
    return (unsigned short)(u >> 16);
}

// ---------------- K0a: dcn_w (o,c,9) -> Wbf[n][o][c] bf16
__global__ __launch_bounds__(256) void k_wbf(fp dcn_w, unsigned short* Wbf){
    int i = blockIdx.x*256 + threadIdx.x;       // 147456
    int c = i & 127, o = (i >> 7) & 127, n = i >> 14;
    Wbf[i] = f2bf(dcn_w[o*1152 + c*9 + n]);
}

// ---------------- K0b: p_w/m_w -> Wpm[n][32q][128c] bf16 (q>=27 zero)
__global__ __launch_bounds__(256) void k_wpm(fp pw, fp mw, unsigned short* Wpm){
    int i = blockIdx.x*256 + threadIdx.x;       // 36864 = 9*32*128
    int c = i & 127, q = (i >> 7) & 31, n = i >> 12;
    float v = 0.f;
    if(q < 18)      v = pw[q*1152 + c*9 + n];
    else if(q < 27) v = mw[(q-18)*1152 + c*9 + n];
    Wpm[i] = f2bf(v);
}

// ---------------- K1: fused upsample+concat+depthwise256 -> Bo (8,256,64,64)
__global__ __launch_bounds__(256) void k_updw256(fp x1, fp x2, fp w, fp bias, float* Bo){
    __shared__ float sA[66*68];
    int bid = blockIdx.x;
    int c = bid & 255, b = bid >> 8;
    int tid = threadIdx.x;
    for(int j = tid; j < 4356; j += 256){
        int r = j / 66, cpos = j - r*66;
        int yy = r - 1, xx = cpos - 1;
        float val = 0.f;
        if(yy >= 0 && yy < 64 && xx >= 0 && xx < 64){
            if(c < 128){
                val = x2[((b*128+c)<<12) + (yy<<6) + xx];
            } else {
                int cc = c - 128;
                const float s = 31.0f/63.0f;
                float fy = yy*s, fx = xx*s;
                int iy = (int)fy; if (iy > 30) iy = 30;
                int ix = (int)fx; if (ix > 30) ix = 30;
                float ty = fy - (float)iy, tx = fx - (float)ix;
                fp src = x1 + ((b*128+cc)<<10);
                float v00 = src[iy*32+ix],     v01 = src[iy*32+ix+1];
                float v10 = src[(iy+1)*32+ix], v11 = src[(iy+1)*32+ix+1];
                val = (v00*(1.f-ty)+v10*ty)*(1.f-tx) + (v01*(1.f-ty)+v11*ty)*tx;
            }
        }
        sA[r*68 + cpos] = val;
    }
    __syncthreads();
    float w0=w[c*9+0], w1=w[c*9+1], w2=w[c*9+2];
    float w3=w[c*9+3], w4=w[c*9+4], w5=w[c*9+5];
    float w6=w[c*9+6], w7=w[c*9+7], w8=w[c*9+8];
    float bv = bias[c];
    float* dst = Bo + ((size_t)(b*256+c)<<12);
    for(int j = tid; j < 4096; j += 256){
        int y = j >> 6, x = j & 63;
        const float* r0 = &sA[y*68 + x];
        float acc = bv
            + w0*r0[0]   + w1*r0[1]   + w2*r0[2]
            + w3*r0[68]  + w4*r0[69]  + w5*r0[70]
            + w6*r0[136] + w7*r0[137] + w8*r0[138];
        dst[j] = acc;
    }
}

// ---------------- K3: pointwise 256->128 + bias -> Ccl (channel-last only)
__global__ __launch_bounds__(256) void k_pw(const float* Bi, fp w, fp bias, float* Ccl){
    __shared__ float sIn[256*32];
    int bid = blockIdx.x;                       // 1024
    int b = bid >> 7;
    int pix0 = (bid & 127) << 5;
    int tid = threadIdx.x;
    for(int j = tid; j < 256*32; j += 256){
        int c = j >> 5, p = j & 31;
        sIn[j] = Bi[((b*256 + c)<<12) + pix0 + p];
    }
    __syncthreads();
    int og = tid >> 3, pg = tid & 7;
    int o0 = og*4, p0 = pg*4;
    float acc[4][4];
    #pragma unroll
    for(int i=0;i<4;i++){ float bv=bias[o0+i];
        #pragma unroll
        for(int j=0;j<4;j++) acc[i][j]=bv; }
    for(int c=0;c<256;c++){
        float4 xv = *(const float4*)&sIn[(c<<5)+p0];
        float w0=w[(o0+0)*256+c], w1=w[(o0+1)*256+c];
        float w2=w[(o0+2)*256+c], w3=w[(o0+3)*256+c];
        acc[0][0]+=w0*xv.x; acc[0][1]+=w0*xv.y; acc[0][2]+=w0*xv.z; acc[0][3]+=w0*xv.w;
        acc[1][0]+=w1*xv.x; acc[1][1]+=w1*xv.y; acc[1][2]+=w1*xv.z; acc[1][3]+=w1*xv.w;
        acc[2][0]+=w2*xv.x; acc[2][1]+=w2*xv.y; acc[2][2]+=w2*xv.z; acc[2][3]+=w2*xv.w;
        acc[3][0]+=w3*xv.x; acc[3][1]+=w3*xv.y; acc[3][2]+=w3*xv.z; acc[3][3]+=w3*xv.w;
    }
    #pragma unroll
    for(int j=0;j<4;j++){
        int px = pix0 + p0 + j;
        *(float4*)&Ccl[((size_t)(b<<12) + px)*128 + o0] =
            make_float4(acc[0][j],acc[1][j],acc[2][j],acc[3][j]);
    }
}

// ---------------- K4: offset(18)+mask(9, sigmoid) 3x3 conv via bf16 MFMA -> OM (8,27,4096)
__global__ __launch_bounds__(256) void k_offmask(fp Ccl, const unsigned short* Wpm,
                                                 fp pb, fp mb, float* OM){
    __shared__ __align__(16) unsigned short sW[32*136];   // [q][c] bf16
    __shared__ __align__(16) unsigned short sX[64*136];   // [px][c] bf16
    int b = blockIdx.x & 7;
    int y = blockIdx.x >> 3;          // output row
    int pix0 = y << 6;
    int tid = threadIdx.x;
    int lane = tid & 63, wave = tid >> 6;
    int m16 = lane & 15, quad = lane >> 4;
    int wp = wave << 4;               // px-subtile
    const float* cb = Ccl + (size_t)(b<<12)*128;

    // ---- probe: D[m][n]=m*(n+100)
    short8 ap = {0,0,0,0,0,0,0,0}, bpr = {0,0,0,0,0,0,0,0};
    if(quad == 0){
        ap[0]  = (short)f2bf((float)m16);
        bpr[0] = (short)f2bf((float)(m16+100));
    }
    f32x4 dp = {0.f,0.f,0.f,0.f};
    dp = __builtin_amdgcn_mfma_f32_16x16x32_bf16(ap, bpr, dp, 0,0,0);
    bool p1 = true;
    #pragma unroll
    for(int r=0;r<4;r++){
        float expP1 = (float)(quad*4+r) * (float)(m16+100);
        p1 = p1 && (fabsf(dp[r]-expP1) < 0.5f);
    }
    bool swapD = (__ballot(p1) != 0xFFFFFFFFFFFFFFFFull);

    f32x4 acc[2];
    acc[0] = (f32x4){0.f,0.f,0.f,0.f};
    acc[1] = (f32x4){0.f,0.f,0.f,0.f};

    for(int n=0;n<9;n++){
        int ky = n/3, kx = n - ky*3;
        int yy = y + ky - 1;
        bool rowok = (yy>=0 && yy<64);
        const int4* wsrc = (const int4*)(Wpm + (n<<12));
        for(int j=tid; j<512; j+=256){
            int q = j >> 4, cg = j & 15;
            *(int4*)&sW[q*136 + (cg<<3)] = wsrc[j];
        }
        #pragma unroll
        for(int it=0; it<8; it++){
            int e = tid + (it<<8);
            int cg = (e & 31) << 2, px = e >> 5;
            int xx = px + kx - 1;
            float4 v = make_float4(0.f,0.f,0.f,0.f);
            if(rowok && xx>=0 && xx<64)
                v = *(const float4*)&cb[(size_t)((yy<<6)+xx)*128 + cg];
            unsigned long long pk = (unsigned long long)f2bf(v.x)
                | ((unsigned long long)f2bf(v.y)<<16)
                | ((unsigned long long)f2bf(v.z)<<32)
                | ((unsigned long long)f2bf(v.w)<<48);
            *(unsigned long long*)&sX[px*136 + cg] = pk;
        }
        __syncthreads();
        #pragma unroll
        for(int ks=0; ks<4; ks++){
            int k0 = ks << 5;
            short8 bfr = *(const short8*)&sX[(wp + m16)*136 + k0 + (quad<<3)];
            #pragma unroll
            for(int qt=0;qt<2;qt++){
                short8 afr = *(const short8*)&sW[((qt<<4) + m16)*136 + k0 + (quad<<3)];
                acc[qt] = __builtin_amdgcn_mfma_f32_16x16x32_bf16(afr, bfr, acc[qt], 0,0,0);
            }
        }
        __syncthreads();
    }
    if(!swapD){
        #pragma unroll
        for(int qt=0;qt<2;qt++){
            int px = pix0 + wp + m16;
            #pragma unroll
            for(int r=0;r<4;r++){
                int q = (qt<<4) + (quad<<2) + r;
                if(q < 27){
                    float v = acc[qt][r] + ((q<18) ? pb[q] : mb[q-18]);
                    if(q>=18) v = 1.f/(1.f+expf(-v));
                    OM[((b*27+q)<<12) + px] = v;
                }
            }
        }
    } else {
        #pragma unroll
        for(int qt=0;qt<2;qt++){
            int q = (qt<<4) + m16;
            if(q < 27){
                float bias = (q<18) ? pb[q] : mb[q-18];
                #pragma unroll
                for(int r=0;r<4;r++){
                    int px = pix0 + wp + (quad<<2) + r;
                    float v = acc[qt][r] + bias;
                    if(q>=18) v = 1.f/(1.f+expf(-v));
                    OM[((b*27+q)<<12) + px] = v;
                }
            }
        }
    }
}

// ---------------- K5: deformable sampling + bf16 MFMA combine (r10 structure)
// + fused BN1-stats epilogue. Grid 512 = 64 tiles x 8 b (b = blockIdx&7).
// All-tap meta in LDS; gather e=tid+it*256 -> cg=(e&31)<<2, px=e>>5: 32 consecutive
// lanes sweep one px's 512B channel row (coalesced, conflict-free b64 LDS writes).
__global__ __launch_bounds__(256) void k_deform(fp Ccl, fp OM, const unsigned short* Wbf,
                                                float* D, float* stats){
    __shared__ __align__(16) unsigned short sW[128*136];  // [o][c] bf16, 272B rows
    __shared__ __align__(16) unsigned short sX[64*136];   // [px][c] bf16
    __shared__ int   sBase[9*64*4];                        // [n][px][corner]
    __shared__ float sGw[9*64*4];
    __shared__ float sd[128], sq[128];
    int b = blockIdx.x & 7;
    int pix0 = (blockIdx.x >> 3) << 6;
    int tid = threadIdx.x;
    int lane = tid & 63, wave = tid >> 6;
    int m16 = lane & 15, quad = lane >> 4;
    int wo = (wave & 1) << 6;       // o-half: 0/64
    int wp = (wave >> 1) << 5;      // px-half: 0/32
    const float* omb = OM + b*27*4096;
    const float* cb  = Ccl + (size_t)(b<<12)*128;
    if(tid < 128){ sd[tid] = 0.f; sq[tid] = 0.f; }

    // ---- probe
    short8 ap = {0,0,0,0,0,0,0,0}, bpr = {0,0,0,0,0,0,0,0};
    if(quad == 0){
        ap[0]  = (short)f2bf((float)m16);
        bpr[0] = (short)f2bf((float)(m16+100));
    }
    f32x4 dp = {0.f,0.f,0.f,0.f};
    dp = __builtin_amdgcn_mfma_f32_16x16x32_bf16(ap, bpr, dp, 0,0,0);
    bool p1 = true;
    #pragma unroll
    for(int r=0;r<4;r++){
        float expP1 = (float)(quad*4+r) * (float)(m16+100);
        p1 = p1 && (fabsf(dp[r]-expP1) < 0.5f);
    }
    bool swapD = (__ballot(p1) != 0xFFFFFFFFFFFFFFFFull);

    f32x4 acc[4][2];
    #pragma unroll
    for(int i=0;i<4;i++){
        #pragma unroll
        for(int j=0;j<2;j++) acc[i][j] = (f32x4){0.f,0.f,0.f,0.f};
    }

    // ---- meta for all 9 taps (576 = 9 n x 64 px)
    for(int i = tid; i < 576; i += 256){
        int n = i >> 6, t = i & 63;
        int pix = pix0 + t, y = pix>>6, x = pix&63;
        float offx = omb[(n<<12)+pix];
        float offy = omb[((n+9)<<12)+pix];
        float m    = omb[((n+18)<<12)+pix];
        float pxf = (float)(y + n/3) + offx;
        float pyf = (float)(x + n%3) + offy;
        float fx = floorf(pxf), fy = floorf(pyf);
        float qx0 = fminf(fmaxf(fx,0.f),65.f), qx1 = fminf(fmaxf(fx+1.f,0.f),65.f);
        float qy0 = fminf(fmaxf(fy,0.f),65.f), qy1 = fminf(fmaxf(fy+1.f,0.f),65.f);
        float pxc = fminf(fmaxf(pxf,0.f),65.f), pyc = fminf(fmaxf(pyf,0.f),65.f);
        float glt = (1.f+(qx0-pxc))*(1.f+(qy0-pyc))*m;
        float grb = (1.f-(qx1-pxc))*(1.f-(qy1-pyc))*m;
        float glb = (1.f+(qx0-pxc))*(1.f-(qy1-pyc))*m;
        float grt = (1.f-(qx1-pxc))*(1.f+(qy0-pyc))*m;
        int ax0=(int)qx0, ax1=(int)qx1, ay0=(int)qy0, ay1=(int)qy1;
        int base = i << 2;
        sBase[base+0] = (ax0>=1&&ax0<=64&&ay0>=1&&ay0<=64) ? (((ax0-1)<<6)+(ay0-1)) : -1;
        sBase[base+1] = (ax1>=1&&ax1<=64&&ay1>=1&&ay1<=64) ? (((ax1-1)<<6)+(ay1-1)) : -1;
        sBase[base+2] = (ax0>=1&&ax0<=64&&ay1>=1&&ay1<=64) ? (((ax0-1)<<6)+(ay1-1)) : -1;
        sBase[base+3] = (ax1>=1&&ax1<=64&&ay0>=1&&ay0<=64) ? (((ax1-1)<<6)+(ay0-1)) : -1;
        sGw[base+0]=glt; sGw[base+1]=grb; sGw[base+2]=glb; sGw[base+3]=grt;
    }
    __syncthreads();

    for(int n=0;n<9;n++){
        {
            const int4* src = (const int4*)(Wbf + (n<<14));
            for(int j = tid; j < 2048; j += 256){
                int o = j >> 4, cg = j & 15;
                *(int4*)&sW[o*136 + (cg<<3)] = src[(o<<4) + cg];
            }
        }
        #pragma unroll
        for(int it=0; it<8; it++){
            int e = tid + (it<<8);
            int cg = (e & 31) << 2, px = e >> 5;
            int mb4 = ((n<<6) + px) << 2;
            const int* bp = &sBase[mb4];
            const float* gp = &sGw[mb4];
            float4 v = make_float4(0.f,0.f,0.f,0.f);
            #pragma unroll
            for(int k=0;k<4;k++){
                int bs = bp[k];
                if(bs>=0){
                    float g = gp[k];
                    float4 r = *(const float4*)&cb[(bs<<7) + cg];
                    v.x += g*r.x; v.y += g*r.y; v.z += g*r.z; v.w += g*r.w;
                }
            }
            unsigned long long pk = (unsigned long long)f2bf(v.x)
                | ((unsigned long long)f2bf(v.y)<<16)
                | ((unsigned long long)f2bf(v.z)<<32)
                | ((unsigned long long)f2bf(v.w)<<48);
            *(unsigned long long*)&sX[px*136 + cg] = pk;
        }
        __syncthreads();
        #pragma unroll
        for(int ks=0; ks<4; ks++){
            int k0 = ks << 5;
            short8 bfr[2];
            #pragma unroll
            for(int pt=0;pt<2;pt++)
                bfr[pt] = *(const short8*)&sX[(wp + (pt<<4) + m16)*136 + k0 + (quad<<3)];
            #pragma unroll
            for(int ot=0;ot<4;ot++){
                short8 afr = *(const short8*)&sW[(wo + (ot<<4) + m16)*136 + k0 + (quad<<3)];
                #pragma unroll
                for(int pt=0;pt<2;pt++)
                    acc[ot][pt] = __builtin_amdgcn_mfma_f32_16x16x32_bf16(afr, bfr[pt], acc[ot][pt], 0,0,0);
            }
        }
        __syncthreads();
    }
    // epilogue: D writes + per-channel sum/sumsq reduction (validated in r11)
    if(!swapD){
        #pragma unroll
        for(int ot=0;ot<4;ot++){
            #pragma unroll
            for(int pt=0;pt<2;pt++){
                int px = pix0 + wp + (pt<<4) + m16;
                #pragma unroll
                for(int r=0;r<4;r++){
                    int o = wo + (ot<<4) + (quad<<2) + r;
                    D[((b*128+o)<<12) + px] = acc[ot][pt][r];
                }
            }
        }
        #pragma unroll
        for(int ot=0;ot<4;ot++){
            #pragma unroll
            for(int r=0;r<4;r++){
                float s = acc[ot][0][r] + acc[ot][1][r];
                float s2 = acc[ot][0][r]*acc[ot][0][r] + acc[ot][1][r]*acc[ot][1][r];
                #pragma unroll
                for(int msk=1; msk<16; msk<<=1){
                    s  += __shfl_xor(s, msk, 64);
                    s2 += __shfl_xor(s2, msk, 64);
                }
                if(m16 == 0){
                    int o = wo + (ot<<4) + (quad<<2) + r;
                    atomicAdd(&sd[o], s);
                    atomicAdd(&sq[o], s2);
                }
            }
        }
    } else {
        #pragma unroll
        for(int ot=0;ot<4;ot++){
            #pragma unroll
            for(int pt=0;pt<2;pt++){
                int o = wo + (ot<<4) + m16;
                #pragma unroll
                for(int r=0;r<4;r++){
                    int px = pix0 + wp + (pt<<4) + (quad<<2) + r;
                    D[((b*128+o)<<12) + px] = acc[ot][pt][r];
                }
            }
        }
        #pragma unroll
        for(int ot=0;ot<4;ot++){
            float s = 0.f, s2 = 0.f;
            #pragma unroll
            for(int pt=0;pt<2;pt++){
                #pragma unroll
                for(int r=0;r<4;r++){
                    float v = acc[ot][pt][r];
                    s += v; s2 += v*v;
                }
            }
            #pragma unroll
            for(int msk=16; msk<64; msk<<=1){
                s  += __shfl_xor(s, msk, 64);
                s2 += __shfl_xor(s2, msk, 64);
            }
            if(quad == 0){
                int o = wo + (ot<<4) + m16;
                atomicAdd(&sd[o], s);
                atomicAdd(&sq[o], s2);
            }
        }
    }
    __syncthreads();
    if(tid < 128){
        atomicAdd(&stats[tid],     sd[tid]);
        atomicAdd(&stats[128+tid], sq[tid]);
    }
}

// ---------------- K7: fused BN1+GELU + depthwise128 -> Hs, + atomic stats2 partials
__global__ __launch_bounds__(256) void k_bngelu_dw128(const float* Dsrc, float* stats,
                                                      fp g1, fp b1, fp w, fp bias, float* Hs){
    __shared__ float sG[66*68];
    __shared__ float sd[256], sq[256];
    int bid = blockIdx.x;
    int c = bid & 127, b = bid >> 7;
    int tid = threadIdx.x;
    float mean1 = stats[c] * (1.f/32768.f);
    float var1  = stats[128+c] * (1.f/32768.f) - mean1*mean1;
    float rstd1 = rsqrtf(var1 + 1e-5f);
    float sc = rstd1 * g1[c];
    float sb = b1[c] - mean1*sc;
    const float* dplane = Dsrc + ((size_t)(b*128+c)<<12);
    for(int j = tid; j < 4356; j += 256){
        int r = j / 66, cpos = j - r*66;
        int yy = r - 1, xx = cpos - 1;
        float val = 0.f;
        if(yy >= 0 && yy < 64 && xx >= 0 && xx < 64){
            float v = dplane[(yy<<6)+xx]*sc + sb;
            val = 0.5f*v*(1.0f + erff(v*0.70710678118654752f));
        }
        sG[r*68 + cpos] = val;
    }
    __syncthreads();
    float w0=w[c*9+0], w1=w[c*9+1], w2=w[c*9+2];
    float w3=w[c*9+3], w4=w[c*9+4], w5=w[c*9+5];
    float w6=w[c*9+6], w7=w[c*9+7], w8=w[c*9+8];
    float bv = bias[c];
    float* dst = Hs + ((size_t)(b*128+c)<<12);
    float s = 0.f, s2 = 0.f;
    for(int j = tid; j < 4096; j += 256){
        int y = j >> 6, x = j & 63;
        const float* r0 = &sG[y*68 + x];
        float acc = bv
            + w0*r0[0]   + w1*r0[1]   + w2*r0[2]
            + w3*r0[68]  + w4*r0[69]  + w5*r0[70]
            + w6*r0[136] + w7*r0[137] + w8*r0[138];
        dst[j] = acc;
        s += acc; s2 += acc*acc;
    }
    sd[tid]=s; sq[tid]=s2; __syncthreads();
    for(int off=128; off>0; off>>=1){
        if(tid<off){ sd[tid]+=sd[tid+off]; sq[tid]+=sq[tid+off]; }
        __syncthreads();
    }
    if(tid==0){
        atomicAdd(&stats[256+c], sd[0]);
        atomicAdd(&stats[384+c], sq[0]);
    }
}

// ---------------- BN2 + ReLU -> f32 out (float4; finalizes stats2 sums inline)
__global__ __launch_bounds__(256) void k_bn_relu_out(const float* Hs, const float* stats, fp g, fp bb, float* out){
    int idx = blockIdx.x*256+threadIdx.x;       // 1,048,576 float4
    int c = (idx>>10)&127;
    float mean2 = stats[256+c] * (1.f/32768.f);
    float var2  = stats[384+c] * (1.f/32768.f) - mean2*mean2;
    float rs = rsqrtf(var2 + 1e-5f) * g[c];
    float sb = bb[c] - mean2*rs;
    float4 v = ((const float4*)Hs)[idx];
    float4 o;
    o.x = fmaxf(v.x*rs+sb, 0.f);
    o.y = fmaxf(v.y*rs+sb, 0.f);
    o.z = fmaxf(v.z*rs+sb, 0.f);
    o.w = fmaxf(v.w*rs+sb, 0.f);
    ((float4*)out)[idx] = o;
}

extern "C" void kernel_launch(void* const* d_in, const int* in_sizes, int n_in,
                              void* d_out, int out_size, void* d_ws, size_t ws_size,
                              hipStream_t stream){
    fp x1   = (fp)d_in[0];
    fp x2   = (fp)d_in[1];
    fp dw_w = (fp)d_in[2];  fp dw_b = (fp)d_in[3];
    fp pw_w = (fp)d_in[4];  fp pw_b = (fp)d_in[5];
    fp p_w  = (fp)d_in[6];  fp p_b  = (fp)d_in[7];
    fp m_w  = (fp)d_in[8];  fp m_b  = (fp)d_in[9];
    fp dcn_w= (fp)d_in[10];
    fp bn1g = (fp)d_in[11]; fp bn1b = (fp)d_in[12];
    fp dw2w = (fp)d_in[13]; fp dw2b = (fp)d_in[14];
    fp bn2g = (fp)d_in[15]; fp bn2b = (fp)d_in[16];

    float* ws  = (float*)d_ws;
    float* Bo  = ws;                    // (8,256,4096) = 8,388,608 f ; D reuses after k_pw
    float* Ccl = ws + 8388608;          // (8,4096,128) = 4,194,304 f ; Hs reuses after k_deform
    float* OM  = ws + 12582912;         // (8,27,4096)  =   884,736 f
    unsigned short* Wbf = (unsigned short*)(ws + 13467648);  // 147,456 bf16 (73,728 f)
    unsigned short* Wpm = (unsigned short*)(ws + 13541376);  //  36,864 bf16 (18,432 f)
    float* stats = ws + 13559808;       // 512 f (sum1, sq1, sum2, sq2)
    float* D   = Bo;                    // Bo dead after k_pw
    float* Hs  = Ccl;                   // Ccl dead after k_deform
    float* out = (float*)d_out;

    hipMemsetAsync(stats, 0, 512*sizeof(float), stream);
    k_wbf          <<<576,   256, 0, stream>>>(dcn_w, Wbf);
    k_wpm          <<<144,   256, 0, stream>>>(p_w, m_w, Wpm);
    k_updw256      <<<2048,  256, 0, stream>>>(x1, x2, dw_w, dw_b, Bo);
    k_pw           <<<1024,  256, 0, stream>>>(Bo, pw_w, pw_b, Ccl);
    k_offmask      <<<512,   256, 0, stream>>>(Ccl, Wpm, p_b, m_b, OM);
    k_deform       <<<512,   256, 0, stream>>>(Ccl, OM, Wbf, D, stats);
    k_bngelu_dw128 <<<1024,  256, 0, stream>>>(D, stats, bn1g, bn1b, dw2w, dw2b, Hs);
    k_bn_relu_out  <<<4096,  256, 0, stream>>>(Hs, stats, bn2g, bn2b, out);
}

// Round 13
// 282.239 us; speedup vs baseline: 1.2886x; 1.0358x over previous
//
#include <hip/hip_runtime.h>
#include <math.h>

// Problem constants: B=8, spatial 64x64 (HW=4096), C_mid=256, C=128, N=9 taps.
// All inputs/outputs are float32.
typedef const float* fp;
typedef __attribute__((ext_vector_type(8))) short short8;   // 8 bf16 = 4 VGPRs (MFMA A/B frag)
typedef __attribute__((ext_vector_type(4))) float f32x4;    // MFMA C/D frag

__device__ __forceinline__ unsigned short f2bf(float f){    // RTNE float->bf16
    unsigned u = __float_as_uint(f);
    u += 0x7fff + ((u >> 16) & 1);
    return (unsigned short)(u >> 16);
}

// ---------------- K0: merged prep — Wbf[n][o][c] bf16, Wpm[n][32q][128c] bf16, Wpwt[c][128o] f32
__global__ __launch_bounds__(256) void k_prep(fp dcn_w, fp pw, fp mw, fp pww,
                                              unsigned short* Wbf, unsigned short* Wpm, float* Wpwt){
    int i = blockIdx.x*256 + threadIdx.x;       // 217088 = 848 blocks
    if(i < 147456){
        int c = i & 127, o = (i >> 7) & 127, n = i >> 14;
        Wbf[i] = f2bf(dcn_w[o*1152 + c*9 + n]);
    } else if(i < 184320){
        int j = i - 147456;
        int c = j & 127, q = (j >> 7) & 31, n = j >> 12;
        float v = 0.f;
        if(q < 18)      v = pw[q*1152 + c*9 + n];
        else if(q < 27) v = mw[(q-18)*1152 + c*9 + n];
        Wpm[j] = f2bf(v);
    } else {
        int j = i - 184320;                     // 32768
        int o = j & 127, c = j >> 7;
        Wpwt[c*128 + o] = pww[o*256 + c];
    }
}

// ---------------- K1: fused upsample+concat+depthwise256 -> Bo (8,256,64,64)
// float4 staging (x2 path) + float4 conv epilogue.
__global__ __launch_bounds__(256) void k_updw256(fp x1, fp x2, fp w, fp bias, float* Bo){
    __shared__ float sA[66*68 + 4];
    int bid = blockIdx.x;
    int c = bid & 255, b = bid >> 8;
    int tid = threadIdx.x;
    // zero halo ring (rows 0/65, cols 0/65) + pad
    for(int j = tid; j < 264; j += 256){
        int idx;
        if(j < 66)       idx = j;
        else if(j < 132) idx = 65*68 + (j-66);
        else if(j < 196) idx = (j-132+1)*68;
        else if(j < 260) idx = (j-196+1)*68 + 65;
        else             idx = 66*68 + (j-260);
        sA[idx] = 0.f;
    }
    if(c < 128){
        const float* src = x2 + ((size_t)(b*128+c)<<12);
        for(int j = tid; j < 1024; j += 256){       // 64 rows x 16 float4
            int yy = j >> 4, x4 = (j & 15) << 2;
            float4 v = *(const float4*)&src[(yy<<6) + x4];
            float* d = &sA[(yy+1)*68 + x4 + 1];
            d[0]=v.x; d[1]=v.y; d[2]=v.z; d[3]=v.w;
        }
    } else {
        int cc = c - 128;
        fp src = x1 + ((b*128+cc)<<10);
        const float s = 31.0f/63.0f;
        for(int j = tid; j < 4096; j += 256){
            int yy = j >> 6, xx = j & 63;
            float fy = yy*s, fx = xx*s;
            int iy = (int)fy; if (iy > 30) iy = 30;
            int ix = (int)fx; if (ix > 30) ix = 30;
            float ty = fy - (float)iy, tx = fx - (float)ix;
            float v00 = src[iy*32+ix],     v01 = src[iy*32+ix+1];
            float v10 = src[(iy+1)*32+ix], v11 = src[(iy+1)*32+ix+1];
            sA[(yy+1)*68 + xx + 1] =
                (v00*(1.f-ty)+v10*ty)*(1.f-tx) + (v01*(1.f-ty)+v11*ty)*tx;
        }
    }
    __syncthreads();
    float w0=w[c*9+0], w1=w[c*9+1], w2=w[c*9+2];
    float w3=w[c*9+3], w4=w[c*9+4], w5=w[c*9+5];
    float w6=w[c*9+6], w7=w[c*9+7], w8=w[c*9+8];
    float bv = bias[c];
    float* dst = Bo + ((size_t)(b*256+c)<<12);
    for(int j = tid; j < 1024; j += 256){           // 64 rows x 16 float4
        int y = j >> 4, x0 = (j & 15) << 2;
        float a0=bv, a1=bv, a2=bv, a3=bv;
        #pragma unroll
        for(int ky=0; ky<3; ky++){
            const float* rr = &sA[(y+ky)*68 + x0];
            float4 u0 = *(const float4*)&rr[0];
            float2 u1 = *(const float2*)&rr[4];
            float wA = (ky==0)?w0:((ky==1)?w3:w6);
            float wB = (ky==0)?w1:((ky==1)?w4:w7);
            float wC = (ky==0)?w2:((ky==1)?w5:w8);
            a0 += wA*u0.x + wB*u0.y + wC*u0.z;
            a1 += wA*u0.y + wB*u0.z + wC*u0.w;
            a2 += wA*u0.z + wB*u0.w + wC*u1.x;
            a3 += wA*u0.w + wB*u1.x + wC*u1.y;
        }
        *(float4*)&dst[(y<<6)+x0] = make_float4(a0,a1,a2,a3);
    }
}

// ---------------- K3: pointwise 256->128 + bias -> Ccl (channel-last), transposed f32 weights
__global__ __launch_bounds__(256) void k_pw(const float* Bi, fp Wt, fp bias, float* Ccl){
    __shared__ float sIn[256*32];
    int bid = blockIdx.x;                       // 1024
    int b = bid >> 7;
    int pix0 = (bid & 127) << 5;
    int tid = threadIdx.x;
    for(int j = tid; j < 256*32; j += 256){
        int c = j >> 5, p = j & 31;
        sIn[j] = Bi[((b*256 + c)<<12) + pix0 + p];
    }
    __syncthreads();
    int og = tid >> 3, pg = tid & 7;
    int o0 = og*4, p0 = pg*4;
    float acc[4][4];
    #pragma unroll
    for(int i=0;i<4;i++){ float bv=bias[o0+i];
        #pragma unroll
        for(int j=0;j<4;j++) acc[i][j]=bv; }
    for(int c=0;c<256;c++){
        float4 xv = *(const float4*)&sIn[(c<<5)+p0];
        float4 w4 = *(const float4*)&Wt[(c<<7)+o0];
        acc[0][0]+=w4.x*xv.x; acc[0][1]+=w4.x*xv.y; acc[0][2]+=w4.x*xv.z; acc[0][3]+=w4.x*xv.w;
        acc[1][0]+=w4.y*xv.x; acc[1][1]+=w4.y*xv.y; acc[1][2]+=w4.y*xv.z; acc[1][3]+=w4.y*xv.w;
        acc[2][0]+=w4.z*xv.x; acc[2][1]+=w4.z*xv.y; acc[2][2]+=w4.z*xv.z; acc[2][3]+=w4.z*xv.w;
        acc[3][0]+=w4.w*xv.x; acc[3][1]+=w4.w*xv.y; acc[3][2]+=w4.w*xv.z; acc[3][3]+=w4.w*xv.w;
    }
    #pragma unroll
    for(int j=0;j<4;j++){
        int px = pix0 + p0 + j;
        *(float4*)&Ccl[((size_t)(b<<12) + px)*128 + o0] =
            make_float4(acc[0][j],acc[1][j],acc[2][j],acc[3][j]);
    }
}

// ---------------- K4: offset(18)+mask(9, sigmoid) 3x3 conv via bf16 MFMA -> OM (8,27,4096)
__global__ __launch_bounds__(256) void k_offmask(fp Ccl, const unsigned short* Wpm,
                                                 fp pb, fp mb, float* OM){
    __shared__ __align__(16) unsigned short sW[32*136];   // [q][c] bf16
    __shared__ __align__(16) unsigned short sX[64*136];   // [px][c] bf16
    int b = blockIdx.x & 7;
    int y = blockIdx.x >> 3;          // output row
    int pix0 = y << 6;
    int tid = threadIdx.x;
    int lane = tid & 63, wave = tid >> 6;
    int m16 = lane & 15, quad = lane >> 4;
    int wp = wave << 4;               // px-subtile
    const float* cb = Ccl + (size_t)(b<<12)*128;

    // ---- probe: D[m][n]=m*(n+100)
    short8 ap = {0,0,0,0,0,0,0,0}, bpr = {0,0,0,0,0,0,0,0};
    if(quad == 0){
        ap[0]  = (short)f2bf((float)m16);
        bpr[0] = (short)f2bf((float)(m16+100));
    }
    f32x4 dp = {0.f,0.f,0.f,0.f};
    dp = __builtin_amdgcn_mfma_f32_16x16x32_bf16(ap, bpr, dp, 0,0,0);
    bool p1 = true;
    #pragma unroll
    for(int r=0;r<4;r++){
        float expP1 = (float)(quad*4+r) * (float)(m16+100);
        p1 = p1 && (fabsf(dp[r]-expP1) < 0.5f);
    }
    bool swapD = (__ballot(p1) != 0xFFFFFFFFFFFFFFFFull);

    f32x4 acc[2];
    acc[0] = (f32x4){0.f,0.f,0.f,0.f};
    acc[1] = (f32x4){0.f,0.f,0.f,0.f};

    for(int n=0;n<9;n++){
        int ky = n/3, kx = n - ky*3;
        int yy = y + ky - 1;
        bool rowok = (yy>=0 && yy<64);
        const int4* wsrc = (const int4*)(Wpm + (n<<12));
        for(int j=tid; j<512; j+=256){
            int q = j >> 4, cg = j & 15;
            *(int4*)&sW[q*136 + (cg<<3)] = wsrc[j];
        }
        #pragma unroll
        for(int it=0; it<8; it++){
            int e = tid + (it<<8);
            int cg = (e & 31) << 2, px = e >> 5;
            int xx = px + kx - 1;
            float4 v = make_float4(0.f,0.f,0.f,0.f);
            if(rowok && xx>=0 && xx<64)
                v = *(const float4*)&cb[(size_t)((yy<<6)+xx)*128 + cg];
            unsigned long long pk = (unsigned long long)f2bf(v.x)
                | ((unsigned long long)f2bf(v.y)<<16)
                | ((unsigned long long)f2bf(v.z)<<32)
                | ((unsigned long long)f2bf(v.w)<<48);
            *(unsigned long long*)&sX[px*136 + cg] = pk;
        }
        __syncthreads();
        #pragma unroll
        for(int ks=0; ks<4; ks++){
            int k0 = ks << 5;
            short8 bfr = *(const short8*)&sX[(wp + m16)*136 + k0 + (quad<<3)];
            #pragma unroll
            for(int qt=0;qt<2;qt++){
                short8 afr = *(const short8*)&sW[((qt<<4) + m16)*136 + k0 + (quad<<3)];
                acc[qt] = __builtin_amdgcn_mfma_f32_16x16x32_bf16(afr, bfr, acc[qt], 0,0,0);
            }
        }
        __syncthreads();
    }
    if(!swapD){
        #pragma unroll
        for(int qt=0;qt<2;qt++){
            int px = pix0 + wp + m16;
            #pragma unroll
            for(int r=0;r<4;r++){
                int q = (qt<<4) + (quad<<2) + r;
                if(q < 27){
                    float v = acc[qt][r] + ((q<18) ? pb[q] : mb[q-18]);
                    if(q>=18) v = 1.f/(1.f+expf(-v));
                    OM[((b*27+q)<<12) + px] = v;
                }
            }
        }
    } else {
        #pragma unroll
        for(int qt=0;qt<2;qt++){
            int q = (qt<<4) + m16;
            if(q < 27){
                float bias = (q<18) ? pb[q] : mb[q-18];
                #pragma unroll
                for(int r=0;r<4;r++){
                    int px = pix0 + wp + (quad<<2) + r;
                    float v = acc[qt][r] + bias;
                    if(q>=18) v = 1.f/(1.f+expf(-v));
                    OM[((b*27+q)<<12) + px] = v;
                }
            }
        }
    }
}

// ---------------- K5: deformable sampling + bf16 MFMA combine (r10 structure, unchanged)
// + fused BN1-stats epilogue. Grid 512 = 64 tiles x 8 b (b = blockIdx&7).
__global__ __launch_bounds__(256) void k_deform(fp Ccl, fp OM, const unsigned short* Wbf,
                                                float* D, float* stats){
    __shared__ __align__(16) unsigned short sW[128*136];  // [o][c] bf16, 272B rows
    __shared__ __align__(16) unsigned short sX[64*136];   // [px][c] bf16
    __shared__ int   sBase[9*64*4];                        // [n][px][corner]
    __shared__ float sGw[9*64*4];
    __shared__ float sd[128], sq[128];
    int b = blockIdx.x & 7;
    int pix0 = (blockIdx.x >> 3) << 6;
    int tid = threadIdx.x;
    int lane = tid & 63, wave = tid >> 6;
    int m16 = lane & 15, quad = lane >> 4;
    int wo = (wave & 1) << 6;       // o-half: 0/64
    int wp = (wave >> 1) << 5;      // px-half: 0/32
    const float* omb = OM + b*27*4096;
    const float* cb  = Ccl + (size_t)(b<<12)*128;
    if(tid < 128){ sd[tid] = 0.f; sq[tid] = 0.f; }

    // ---- probe
    short8 ap = {0,0,0,0,0,0,0,0}, bpr = {0,0,0,0,0,0,0,0};
    if(quad == 0){
        ap[0]  = (short)f2bf((float)m16);
        bpr[0] = (short)f2bf((float)(m16+100));
    }
    f32x4 dp = {0.f,0.f,0.f,0.f};
    dp = __builtin_amdgcn_mfma_f32_16x16x32_bf16(ap, bpr, dp, 0,0,0);
    bool p1 = true;
    #pragma unroll
    for(int r=0;r<4;r++){
        float expP1 = (float)(quad*4+r) * (float)(m16+100);
        p1 = p1 && (fabsf(dp[r]-expP1) < 0.5f);
    }
    bool swapD = (__ballot(p1) != 0xFFFFFFFFFFFFFFFFull);

    f32x4 acc[4][2];
    #pragma unroll
    for(int i=0;i<4;i++){
        #pragma unroll
        for(int j=0;j<2;j++) acc[i][j] = (f32x4){0.f,0.f,0.f,0.f};
    }

    // ---- meta for all 9 taps (576 = 9 n x 64 px)
    for(int i = tid; i < 576; i += 256){
        int n = i >> 6, t = i & 63;
        int pix = pix0 + t, y = pix>>6, x = pix&63;
        float offx = omb[(n<<12)+pix];
        float offy = omb[((n+9)<<12)+pix];
        float m    = omb[((n+18)<<12)+pix];
        float pxf = (float)(y + n/3) + offx;
        float pyf = (float)(x + n%3) + offy;
        float fx = floorf(pxf), fy = floorf(pyf);
        float qx0 = fminf(fmaxf(fx,0.f),65.f), qx1 = fminf(fmaxf(fx+1.f,0.f),65.f);
        float qy0 = fminf(fmaxf(fy,0.f),65.f), qy1 = fminf(fmaxf(fy+1.f,0.f),65.f);
        float pxc = fminf(fmaxf(pxf,0.f),65.f), pyc = fminf(fmaxf(pyf,0.f),65.f);
        float glt = (1.f+(qx0-pxc))*(1.f+(qy0-pyc))*m;
        float grb = (1.f-(qx1-pxc))*(1.f-(qy1-pyc))*m;
        float glb = (1.f+(qx0-pxc))*(1.f-(qy1-pyc))*m;
        float grt = (1.f-(qx1-pxc))*(1.f+(qy0-pyc))*m;
        int ax0=(int)qx0, ax1=(int)qx1, ay0=(int)qy0, ay1=(int)qy1;
        int base = i << 2;
        sBase[base+0] = (ax0>=1&&ax0<=64&&ay0>=1&&ay0<=64) ? (((ax0-1)<<6)+(ay0-1)) : -1;
        sBase[base+1] = (ax1>=1&&ax1<=64&&ay1>=1&&ay1<=64) ? (((ax1-1)<<6)+(ay1-1)) : -1;
        sBase[base+2] = (ax0>=1&&ax0<=64&&ay1>=1&&ay1<=64) ? (((ax0-1)<<6)+(ay1-1)) : -1;
        sBase[base+3] = (ax1>=1&&ax1<=64&&ay0>=1&&ay0<=64) ? (((ax1-1)<<6)+(ay0-1)) : -1;
        sGw[base+0]=glt; sGw[base+1]=grb; sGw[base+2]=glb; sGw[base+3]=grt;
    }
    __syncthreads();

    for(int n=0;n<9;n++){
        {
            const int4* src = (const int4*)(Wbf + (n<<14));
            for(int j = tid; j < 2048; j += 256){
                int o = j >> 4, cg = j & 15;
                *(int4*)&sW[o*136 + (cg<<3)] = src[(o<<4) + cg];
            }
        }
        #pragma unroll
        for(int it=0; it<8; it++){
            int e = tid + (it<<8);
            int cg = (e & 31) << 2, px = e >> 5;
            int mb4 = ((n<<6) + px) << 2;
            const int* bp = &sBase[mb4];
            const float* gp = &sGw[mb4];
            float4 v = make_float4(0.f,0.f,0.f,0.f);
            #pragma unroll
            for(int k=0;k<4;k++){
                int bs = bp[k];
                if(bs>=0){
                    float g = gp[k];
                    float4 r = *(const float4*)&cb[(bs<<7) + cg];
                    v.x += g*r.x; v.y += g*r.y; v.z += g*r.z; v.w += g*r.w;
                }
            }
            unsigned long long pk = (unsigned long long)f2bf(v.x)
                | ((unsigned long long)f2bf(v.y)<<16)
                | ((unsigned long long)f2bf(v.z)<<32)
                | ((unsigned long long)f2bf(v.w)<<48);
            *(unsigned long long*)&sX[px*136 + cg] = pk;
        }
        __syncthreads();
        #pragma unroll
        for(int ks=0; ks<4; ks++){
            int k0 = ks << 5;
            short8 bfr[2];
            #pragma unroll
            for(int pt=0;pt<2;pt++)
                bfr[pt] = *(const short8*)&sX[(wp + (pt<<4) + m16)*136 + k0 + (quad<<3)];
            #pragma unroll
            for(int ot=0;ot<4;ot++){
                short8 afr = *(const short8*)&sW[(wo + (ot<<4) + m16)*136 + k0 + (quad<<3)];
                #pragma unroll
                for(int pt=0;pt<2;pt++)
                    acc[ot][pt] = __builtin_amdgcn_mfma_f32_16x16x32_bf16(afr, bfr[pt], acc[ot][pt], 0,0,0);
            }
        }
        __syncthreads();
    }
    // epilogue: D writes + per-channel sum/sumsq reduction
    if(!swapD){
        #pragma unroll
        for(int ot=0;ot<4;ot++){
            #pragma unroll
            for(int pt=0;pt<2;pt++){
                int px = pix0 + wp + (pt<<4) + m16;
                #pragma unroll
                for(int r=0;r<4;r++){
                    int o = wo + (ot<<4) + (quad<<2) + r;
                    D[((b*128+o)<<12) + px] = acc[ot][pt][r];
                }
            }
        }
        #pragma unroll
        for(int ot=0;ot<4;ot++){
            #pragma unroll
            for(int r=0;r<4;r++){
                float s = acc[ot][0][r] + acc[ot][1][r];
                float s2 = acc[ot][0][r]*acc[ot][0][r] + acc[ot][1][r]*acc[ot][1][r];
                #pragma unroll
                for(int msk=1; msk<16; msk<<=1){
                    s  += __shfl_xor(s, msk, 64);
                    s2 += __shfl_xor(s2, msk, 64);
                }
                if(m16 == 0){
                    int o = wo + (ot<<4) + (quad<<2) + r;
                    atomicAdd(&sd[o], s);
                    atomicAdd(&sq[o], s2);
                }
            }
        }
    } else {
        #pragma unroll
        for(int ot=0;ot<4;ot++){
            #pragma unroll
            for(int pt=0;pt<2;pt++){
                int o = wo + (ot<<4) + m16;
                #pragma unroll
                for(int r=0;r<4;r++){
                    int px = pix0 + wp + (pt<<4) + (quad<<2) + r;
                    D[((b*128+o)<<12) + px] = acc[ot][pt][r];
                }
            }
        }
        #pragma unroll
        for(int ot=0;ot<4;ot++){
            float s = 0.f, s2 = 0.f;
            #pragma unroll
            for(int pt=0;pt<2;pt++){
                #pragma unroll
                for(int r=0;r<4;r++){
                    float v = acc[ot][pt][r];
                    s += v; s2 += v*v;
                }
            }
            #pragma unroll
            for(int msk=16; msk<64; msk<<=1){
                s  += __shfl_xor(s, msk, 64);
                s2 += __shfl_xor(s2, msk, 64);
            }
            if(quad == 0){
                int o = wo + (ot<<4) + m16;
                atomicAdd(&sd[o], s);
                atomicAdd(&sq[o], s2);
            }
        }
    }
    __syncthreads();
    if(tid < 128){
        atomicAdd(&stats[tid],     sd[tid]);
        atomicAdd(&stats[128+tid], sq[tid]);
    }
}

// ---------------- K7: fused BN1+GELU + depthwise128 -> Hs, + atomic stats2 partials
// float4 staging + float4 conv epilogue.
__global__ __launch_bounds__(256) void k_bngelu_dw128(const float* Dsrc, float* stats,
                                                      fp g1, fp b1, fp w, fp bias, float* Hs){
    __shared__ float sG[66*68 + 4];
    __shared__ float sd[256], sq[256];
    int bid = blockIdx.x;
    int c = bid & 127, b = bid >> 7;
    int tid = threadIdx.x;
    float mean1 = stats[c] * (1.f/32768.f);
    float var1  = stats[128+c] * (1.f/32768.f) - mean1*mean1;
    float rstd1 = rsqrtf(var1 + 1e-5f);
    float sc = rstd1 * g1[c];
    float sb = b1[c] - mean1*sc;
    // zero halo ring
    for(int j = tid; j < 264; j += 256){
        int idx;
        if(j < 66)       idx = j;
        else if(j < 132) idx = 65*68 + (j-66);
        else if(j < 196) idx = (j-132+1)*68;
        else if(j < 260) idx = (j-196+1)*68 + 65;
        else             idx = 66*68 + (j-260);
        sG[idx] = 0.f;
    }
    const float* dplane = Dsrc + ((size_t)(b*128+c)<<12);
    for(int j = tid; j < 1024; j += 256){           // 64 rows x 16 float4, BN1+GELU
        int yy = j >> 4, x4 = (j & 15) << 2;
        float4 v = *(const float4*)&dplane[(yy<<6) + x4];
        float g0 = v.x*sc+sb, g1v = v.y*sc+sb, g2 = v.z*sc+sb, g3 = v.w*sc+sb;
        float* d = &sG[(yy+1)*68 + x4 + 1];
        d[0] = 0.5f*g0*(1.0f + erff(g0*0.70710678118654752f));
        d[1] = 0.5f*g1v*(1.0f + erff(g1v*0.70710678118654752f));
        d[2] = 0.5f*g2*(1.0f + erff(g2*0.70710678118654752f));
        d[3] = 0.5f*g3*(1.0f + erff(g3*0.70710678118654752f));
    }
    __syncthreads();
    float w0=w[c*9+0], w1=w[c*9+1], w2=w[c*9+2];
    float w3=w[c*9+3], w4=w[c*9+4], w5=w[c*9+5];
    float w6=w[c*9+6], w7=w[c*9+7], w8=w[c*9+8];
    float bv = bias[c];
    float* dst = Hs + ((size_t)(b*128+c)<<12);
    float s = 0.f, s2 = 0.f;
    for(int j = tid; j < 1024; j += 256){           // 64 rows x 16 float4
        int y = j >> 4, x0 = (j & 15) << 2;
        float a0=bv, a1=bv, a2=bv, a3=bv;
        #pragma unroll
        for(int ky=0; ky<3; ky++){
            const float* rr = &sG[(y+ky)*68 + x0];
            float4 u0 = *(const float4*)&rr[0];
            float2 u1 = *(const float2*)&rr[4];
            float wA = (ky==0)?w0:((ky==1)?w3:w6);
            float wB = (ky==0)?w1:((ky==1)?w4:w7);
            float wC = (ky==0)?w2:((ky==1)?w5:w8);
            a0 += wA*u0.x + wB*u0.y + wC*u0.z;
            a1 += wA*u0.y + wB*u0.z + wC*u0.w;
            a2 += wA*u0.z + wB*u0.w + wC*u1.x;
            a3 += wA*u0.w + wB*u1.x + wC*u1.y;
        }
        *(float4*)&dst[(y<<6)+x0] = make_float4(a0,a1,a2,a3);
        s += a0+a1+a2+a3;
        s2 += a0*a0 + a1*a1 + a2*a2 + a3*a3;
    }
    sd[tid]=s; sq[tid]=s2; __syncthreads();
    for(int off=128; off>0; off>>=1){
        if(tid<off){ sd[tid]+=sd[tid+off]; sq[tid]+=sq[tid+off]; }
        __syncthreads();
    }
    if(tid==0){
        atomicAdd(&stats[256+c], sd[0]);
        atomicAdd(&stats[384+c], sq[0]);
    }
}

// ---------------- BN2 + ReLU -> f32 out (float4; finalizes stats2 sums inline)
__global__ __launch_bounds__(256) void k_bn_relu_out(const float* Hs, const float* stats, fp g, fp bb, float* out){
    int idx = blockIdx.x*256+threadIdx.x;       // 1,048,576 float4
    int c = (idx>>10)&127;
    float mean2 = stats[256+c] * (1.f/32768.f);
    float var2  = stats[384+c] * (1.f/32768.f) - mean2*mean2;
    float rs = rsqrtf(var2 + 1e-5f) * g[c];
    float sb = bb[c] - mean2*rs;
    float4 v = ((const float4*)Hs)[idx];
    float4 o;
    o.x = fmaxf(v.x*rs+sb, 0.f);
    o.y = fmaxf(v.y*rs+sb, 0.f);
    o.z = fmaxf(v.z*rs+sb, 0.f);
    o.w = fmaxf(v.w*rs+sb, 0.f);
    ((float4*)out)[idx] = o;
}

extern "C" void kernel_launch(void* const* d_in, const int* in_sizes, int n_in,
                              void* d_out, int out_size, void* d_ws, size_t ws_size,
                              hipStream_t stream){
    fp x1   = (fp)d_in[0];
    fp x2   = (fp)d_in[1];
    fp dw_w = (fp)d_in[2];  fp dw_b = (fp)d_in[3];
    fp pw_w = (fp)d_in[4];  fp pw_b = (fp)d_in[5];
    fp p_w  = (fp)d_in[6];  fp p_b  = (fp)d_in[7];
    fp m_w  = (fp)d_in[8];  fp m_b  = (fp)d_in[9];
    fp dcn_w= (fp)d_in[10];
    fp bn1g = (fp)d_in[11]; fp bn1b = (fp)d_in[12];
    fp dw2w = (fp)d_in[13]; fp dw2b = (fp)d_in[14];
    fp bn2g = (fp)d_in[15]; fp bn2b = (fp)d_in[16];

    float* ws  = (float*)d_ws;
    float* Bo  = ws;                    // (8,256,4096) = 8,388,608 f ; D reuses after k_pw
    float* Ccl = ws + 8388608;          // (8,4096,128) = 4,194,304 f ; Hs reuses after k_deform
    float* OM  = ws + 12582912;         // (8,27,4096)  =   884,736 f
    unsigned short* Wbf = (unsigned short*)(ws + 13467648);  // 147,456 bf16 (73,728 f)
    unsigned short* Wpm = (unsigned short*)(ws + 13541376);  //  36,864 bf16 (18,432 f)
    float* stats = ws + 13559808;       // 512 f (sum1, sq1, sum2, sq2)
    float* Wpwt  = ws + 13560320;       // 32,768 f (pw_w transposed [c][o])
    float* D   = Bo;                    // Bo dead after k_pw
    float* Hs  = Ccl;                   // Ccl dead after k_deform
    float* out = (float*)d_out;

    hipMemsetAsync(stats, 0, 512*sizeof(float), stream);
    k_prep         <<<848,   256, 0, stream>>>(dcn_w, p_w, m_w, pw_w, Wbf, Wpm, Wpwt);
    k_updw256      <<<2048,  256, 0, stream>>>(x1, x2, dw_w, dw_b, Bo);
    k_pw           <<<1024,  256, 0, stream>>>(Bo, Wpwt, pw_b, Ccl);
    k_offmask      <<<512,   256, 0, stream>>>(Ccl, Wpm, p_b, m_b, OM);
    k_deform       <<<512,   256, 0, stream>>>(Ccl, OM, Wbf, D, stats);
    k_bngelu_dw128 <<<1024,  256, 0, stream>>>(D, stats, bn1g, bn1b, dw2w, dw2b, Hs);
    k_bn_relu_out  <<<4096,  256, 0, stream>>>(Hs, stats, bn2g, bn2b, out);
}